// Round 2
// baseline (465.484 us; speedup 1.0000x reference)
//
#include <hip/hip_runtime.h>
#include <hip/hip_bf16.h>

#define TT 4096
#define EE 512
#define AA 128

typedef short short8 __attribute__((ext_vector_type(8)));
typedef float f32x4 __attribute__((ext_vector_type(4)));

__device__ __forceinline__ short f2bf(float f) {
    union { float f; unsigned u; } v; v.f = f;
    unsigned r = v.u + 0x7fffu + ((v.u >> 16) & 1u);
    return (short)(r >> 16);
}

// ws layout (bytes)
#define WS_WVT   0           // bf16 [128][544]  : Wv^T columns 0..511, M^T columns 512..543
#define WS_QBIAS 139264      // f32 [32][128]    : query@Wq + bv + att_b
#define WS_NV    155648      // f32 [128]        : normalized att_v
#define WS_P     156160      // f32 [32][4096]   : sigmoid probabilities
#define WS_PART  680448      // f32 [32][8][512] : attn_c partials

// ---------------------------------------------------------------- prep 1
// wvt[a][k] = Wv[k][a] for k<512 ; M[k-512][a] = sum_c conv_k[k-512][c]*Wl[c][a]
// for 512<=k<543 ; 0 for k==543
__global__ void prep_wvt(const float* __restrict__ Wv, const float* __restrict__ conv_k,
                         const float* __restrict__ Wl, short* __restrict__ wvt) {
    int idx = blockIdx.x * 256 + threadIdx.x;   // 0..69631  (128*544)
    int a = idx / 544, k = idx % 544;
    float val = 0.f;
    if (k < 512) {
        val = Wv[k * 128 + a];
    } else if (k < 543) {
        int kk = k - 512;
        float s = 0.f;
        #pragma unroll
        for (int c = 0; c < 32; ++c) s += conv_k[kk * 32 + c] * Wl[c * 128 + a];
        val = s;
    }
    wvt[a * 544 + k] = f2bf(val);
}

// ---------------------------------------------------------------- prep 2
__global__ void prep_qbias(const float* __restrict__ query, const float* __restrict__ Wq,
                           const float* __restrict__ bv, const float* __restrict__ att_b,
                           const float* __restrict__ att_v, const float* __restrict__ att_g,
                           float* __restrict__ q_bias, float* __restrict__ nv) {
    int b = blockIdx.x, a = threadIdx.x;   // 32 blocks x 128 threads
    float s = 0.f;
    for (int d = 0; d < 512; ++d) s += query[b * 512 + d] * Wq[d * 128 + a];
    q_bias[b * 128 + a] = s + bv[a] + att_b[a];
    if (b == 0) {
        float ss = 0.f;
        for (int i = 0; i < 128; ++i) { float t = att_v[i]; ss += t * t; }
        nv[a] = att_g[0] * att_v[a] * rsqrtf(ss);
    }
}

// ---------------------------------------------------------------- energy GEMM
// rows = (b,t), K = 512 (value@Wv) + 32 (location band conv), N = 128
// epilogue: tanh, dot nv, mask, sigmoid -> p_buf[b][t]
__global__ __launch_bounds__(256) void energy_kernel(
    const float* __restrict__ value, const int* __restrict__ vlen,
    const float* __restrict__ accum, const short* __restrict__ wvt,
    const float* __restrict__ q_bias, const float* __restrict__ nv,
    const float* __restrict__ score_bias, float* __restrict__ p_buf) {

    __shared__ __align__(16) short As[64 * 40];   // 64 rows x 32 k, stride 40 (bank spread)
    __shared__ __align__(16) short Bs[128 * 40];  // 128 a  x 32 k, stride 40

    int bid = blockIdx.x;
    int b  = bid >> 6;             // 64 tiles per batch row (T/64)
    int t0 = (bid & 63) << 6;
    int tid = threadIdx.x;
    int l = tid & 63, w = tid >> 6;
    int l15 = l & 15, g = l >> 4;

    f32x4 acc[8];
    #pragma unroll
    for (int i = 0; i < 8; ++i) acc[i] = (f32x4){0.f, 0.f, 0.f, 0.f};

    int ar = tid >> 2;            // A staging: row 0..63
    int ac = (tid & 3) * 8;       // k-offset 0,8,16,24
    int br = tid >> 1;            // B staging: a-row 0..127
    int bc = (tid & 1) * 16;      // k-offset 0,16

    const float* aglob = value + ((size_t)(b * TT + t0 + ar)) * EE;

    for (int kc = 0; kc < 17; ++kc) {
        // --- stage B chunk (bf16, L2-resident panel)
        {
            const short* src = wvt + br * 544 + kc * 32 + bc;
            short8 s0 = *(const short8*)(src);
            short8 s1 = *(const short8*)(src + 8);
            *(short8*)(&Bs[br * 40 + bc])     = s0;
            *(short8*)(&Bs[br * 40 + bc + 8]) = s1;
        }
        // --- stage A chunk
        if (kc < 16) {
            const float4* src = (const float4*)(aglob + kc * 32 + ac);
            float4 v0 = src[0], v1 = src[1];
            short8 h;
            h[0] = f2bf(v0.x); h[1] = f2bf(v0.y); h[2] = f2bf(v0.z); h[3] = f2bf(v0.w);
            h[4] = f2bf(v1.x); h[5] = f2bf(v1.y); h[6] = f2bf(v1.z); h[7] = f2bf(v1.w);
            *(short8*)(&As[ar * 40 + ac]) = h;
        } else {
            // band matrix: As[r][kk] = accum[b, t0+r-15+kk], zero padded, col 31 = 0
            short8 h;
            #pragma unroll
            for (int i = 0; i < 8; ++i) {
                int kk = ac + i;
                int t = t0 + ar - 15 + kk;
                float v = (kk < 31 && t >= 0 && t < TT) ? accum[b * TT + t] : 0.f;
                h[i] = f2bf(v);
            }
            *(short8*)(&As[ar * 40 + ac]) = h;
        }
        __syncthreads();

        // --- compute: wave w owns rows w*16..w*16+15, all 128 cols
        short8 af = *(const short8*)(&As[(w * 16 + l15) * 40 + g * 8]);
        #pragma unroll
        for (int t8 = 0; t8 < 8; ++t8) {
            short8 bf = *(const short8*)(&Bs[(t8 * 16 + l15) * 40 + g * 8]);
            acc[t8] = __builtin_amdgcn_mfma_f32_16x16x32_bf16(af, bf, acc[t8], 0, 0, 0);
        }
        __syncthreads();
    }

    // --- epilogue: energy -> p
    float qb[8], nvv[8];
    #pragma unroll
    for (int t8 = 0; t8 < 8; ++t8) {
        int a = t8 * 16 + l15;
        qb[t8]  = q_bias[b * 128 + a];
        nvv[t8] = nv[a];
    }
    int len = vlen[b];
    float sb = score_bias[0];
    #pragma unroll
    for (int j = 0; j < 4; ++j) {
        float e = 0.f;
        #pragma unroll
        for (int t8 = 0; t8 < 8; ++t8)
            e += tanhf(acc[t8][j] + qb[t8]) * nvv[t8];
        // reduce over the 16 col-lanes (C/D col = lane&15)
        e += __shfl_xor(e, 1);
        e += __shfl_xor(e, 2);
        e += __shfl_xor(e, 4);
        e += __shfl_xor(e, 8);
        if (l15 == 0) {
            int t = t0 + w * 16 + g * 4 + j;
            float p = 0.f;
            if (t < len) { float ee = e + sb; p = 1.f / (1.f + expf(-ee)); }
            p_buf[b * TT + t] = p;
        }
    }
}

// ---------------------------------------------------------------- attn_weight (elementwise)
__global__ void weight_kernel(const float* __restrict__ p_buf, const float* __restrict__ prev,
                              float* __restrict__ outw) {
    int i = blockIdx.x * 256 + threadIdx.x;    // 0..131071
    int t = i & (TT - 1);
    float w = prev[i] * p_buf[i];
    if (t > 0) w += prev[i - 1] * (1.f - p_buf[i - 1]);
    outw[i] = w;
}

// ---------------------------------------------------------------- attn_c partials
__global__ __launch_bounds__(256) void ctx_partial(const float* __restrict__ value,
                                                   const float* __restrict__ wbuf,
                                                   float* __restrict__ part) {
    __shared__ float wsm[512];
    int b = blockIdx.x, tc = blockIdx.y;
    int tid = threadIdx.x;
    wsm[tid]       = wbuf[b * TT + tc * 512 + tid];
    wsm[tid + 256] = wbuf[b * TT + tc * 512 + tid + 256];
    __syncthreads();
    float ax = 0.f, ay = 0.f;
    const float* vbase = value + ((size_t)b * TT + tc * 512) * EE + tid * 2;
    for (int tt = 0; tt < 512; ++tt) {
        float wv = wsm[tt];
        if (wv != 0.f) {   // block-uniform skip: weights are near-one-hot sparse
            float2 v = *(const float2*)(vbase + (size_t)tt * EE);
            ax += wv * v.x; ay += wv * v.y;
        }
    }
    float2 r; r.x = ax; r.y = ay;
    *(float2*)(part + ((b * 8 + tc) * 512) + tid * 2) = r;
}

// ---------------------------------------------------------------- attn_c reduce
__global__ void ctx_reduce(const float* __restrict__ part, float* __restrict__ outc) {
    int idx = blockIdx.x * 256 + threadIdx.x;  // 0..16383
    int b = idx >> 9, e = idx & 511;
    float s = 0.f;
    #pragma unroll
    for (int tc = 0; tc < 8; ++tc) s += part[(b * 8 + tc) * 512 + e];
    outc[idx] = s;
}

// ---------------------------------------------------------------- launch
extern "C" void kernel_launch(void* const* d_in, const int* in_sizes, int n_in,
                              void* d_out, int out_size, void* d_ws, size_t ws_size,
                              hipStream_t stream) {
    const float* value  = (const float*)d_in[0];
    const int*   vlen   = (const int*)  d_in[1];
    const float* query  = (const float*)d_in[2];
    const float* accum  = (const float*)d_in[3];
    const float* prev   = (const float*)d_in[4];
    const float* Wv     = (const float*)d_in[5];
    const float* bv     = (const float*)d_in[6];
    const float* Wq     = (const float*)d_in[7];
    const float* conv_k = (const float*)d_in[8];
    const float* Wl     = (const float*)d_in[9];
    const float* att_v  = (const float*)d_in[10];
    const float* att_g  = (const float*)d_in[11];
    const float* att_b  = (const float*)d_in[12];
    const float* sbias  = (const float*)d_in[13];

    char* wsb = (char*)d_ws;
    short* wvt   = (short*)(wsb + WS_WVT);
    float* qbias = (float*)(wsb + WS_QBIAS);
    float* nv    = (float*)(wsb + WS_NV);
    float* pbuf  = (float*)(wsb + WS_P);
    float* part  = (float*)(wsb + WS_PART);

    float* outc = (float*)d_out;             // [32,512]
    float* outw = (float*)d_out + 32 * 512;  // [32,4096]

    prep_wvt   <<<272, 256, 0, stream>>>(Wv, conv_k, Wl, wvt);
    prep_qbias <<<32, 128, 0, stream>>>(query, Wq, bv, att_b, att_v, att_g, qbias, nv);
    energy_kernel<<<2048, 256, 0, stream>>>(value, vlen, accum, wvt, qbias, nv, sbias, pbuf);
    weight_kernel<<<512, 256, 0, stream>>>(pbuf, prev, outw);
    ctx_partial<<<dim3(32, 8), 256, 0, stream>>>(value, outw, part);
    ctx_reduce <<<64, 256, 0, stream>>>(part, outc);
}